// Round 4
// baseline (491.105 us; speedup 1.0000x reference)
//
#include <hip/hip_runtime.h>

#define N_NODES 50000
#define N_EDGES 800000
#define IN_F 256
#define OUT_F 64
#define HEADS 4
#define HF 256  // HEADS*OUT_F
#define NEG_SLOPE 0.2f

// ---- monotone float<->uint encoding for atomicMax on floats ----
__device__ __forceinline__ unsigned encf(float f) {
  unsigned u = __float_as_uint(f);
  return (u & 0x80000000u) ? ~u : (u | 0x80000000u);
}
__device__ __forceinline__ float decf(unsigned k) {
  unsigned u = (k & 0x80000000u) ? (k & 0x7FFFFFFFu) : ~k;
  return __uint_as_float(u);
}

// ---- Kernel 1: h = x @ W per head, fused attn-logit epilogue ----
__global__ __launch_bounds__(256) void k_gemm(const float* __restrict__ x,
                                              const float* __restrict__ W,
                                              const float* __restrict__ a_src,
                                              const float* __restrict__ a_dst,
                                              float* __restrict__ h,
                                              float* __restrict__ as_out,
                                              float* __restrict__ ad_out) {
  __shared__ __align__(16) float xs[32][68];
  __shared__ __align__(16) float ws[32][64];
  const int t = threadIdx.x;
  const int n0 = blockIdx.x * 64;
  const int hd = blockIdx.y;
  const int f0 = (t & 15) * 4;
  const int m0 = (t >> 4) * 4;
  const float* Wh = W + hd * (IN_F * OUT_F);

  float acc[4][4];
#pragma unroll
  for (int i = 0; i < 4; i++)
#pragma unroll
    for (int j = 0; j < 4; j++) acc[i][j] = 0.f;

  for (int k0 = 0; k0 < IN_F; k0 += 32) {
#pragma unroll
    for (int qq = 0; qq < 2; qq++) {
      int q = t + qq * 256;
      int row = q >> 3, c4 = q & 7;
      int gr = n0 + row;
      gr = gr < N_NODES ? gr : (N_NODES - 1);
      float4 v = *(const float4*)(x + (size_t)gr * IN_F + k0 + c4 * 4);
      xs[c4 * 4 + 0][row] = v.x;
      xs[c4 * 4 + 1][row] = v.y;
      xs[c4 * 4 + 2][row] = v.z;
      xs[c4 * 4 + 3][row] = v.w;
    }
#pragma unroll
    for (int qq = 0; qq < 2; qq++) {
      int q = t + qq * 256;
      int kk = q >> 4, o4 = q & 15;
      *(float4*)(&ws[kk][o4 * 4]) = *(const float4*)(Wh + (size_t)(k0 + kk) * OUT_F + o4 * 4);
    }
    __syncthreads();
#pragma unroll
    for (int kk = 0; kk < 32; kk++) {
      float4 a = *(const float4*)(&xs[kk][m0]);
      float4 b = *(const float4*)(&ws[kk][f0]);
      acc[0][0] += a.x * b.x; acc[0][1] += a.x * b.y; acc[0][2] += a.x * b.z; acc[0][3] += a.x * b.w;
      acc[1][0] += a.y * b.x; acc[1][1] += a.y * b.y; acc[1][2] += a.y * b.z; acc[1][3] += a.y * b.w;
      acc[2][0] += a.z * b.x; acc[2][1] += a.z * b.y; acc[2][2] += a.z * b.z; acc[2][3] += a.z * b.w;
      acc[3][0] += a.w * b.x; acc[3][1] += a.w * b.y; acc[3][2] += a.w * b.z; acc[3][3] += a.w * b.w;
    }
    __syncthreads();
  }
#pragma unroll
  for (int i = 0; i < 4; i++) {
    int m = n0 + m0 + i;
    if (m < N_NODES) {
      float4 v = make_float4(acc[i][0], acc[i][1], acc[i][2], acc[i][3]);
      *(float4*)(h + (size_t)m * HF + hd * OUT_F + f0) = v;
    }
  }
  // fused attention-logit epilogue
  const float4 asv = *(const float4*)(a_src + hd * OUT_F + f0);
  const float4 adv = *(const float4*)(a_dst + hd * OUT_F + f0);
  float ps[4], pd[4];
#pragma unroll
  for (int i = 0; i < 4; i++) {
    ps[i] = acc[i][0] * asv.x + acc[i][1] * asv.y + acc[i][2] * asv.z + acc[i][3] * asv.w;
    pd[i] = acc[i][0] * adv.x + acc[i][1] * adv.y + acc[i][2] * adv.z + acc[i][3] * adv.w;
  }
#pragma unroll
  for (int off = 8; off > 0; off >>= 1) {
#pragma unroll
    for (int i = 0; i < 4; i++) {
      ps[i] += __shfl_down(ps[i], off, 16);
      pd[i] += __shfl_down(pd[i], off, 16);
    }
  }
  if ((t & 15) == 0) {
#pragma unroll
    for (int i = 0; i < 4; i++) {
      int m = n0 + m0 + i;
      if (m < N_NODES) {
        as_out[hd * N_NODES + m] = ps[i];
        ad_out[hd * N_NODES + m] = pd[i];
      }
    }
  }
}

// ---- Kernel 2: global max of e over [H,E] + dst-degree histogram ----
__global__ __launch_bounds__(256) void k_edge_max(const int* __restrict__ src,
                                                  const int* __restrict__ dst,
                                                  const float* __restrict__ ew,
                                                  const float* __restrict__ as,
                                                  const float* __restrict__ ad,
                                                  unsigned* __restrict__ gmax,
                                                  int* __restrict__ deg) {
  int e = blockIdx.x * 256 + threadIdx.x;
  int s = src[e], d = dst[e];
  float w = ew[e];
  atomicAdd(deg + d, 1);
  float m = -3.4e38f;
#pragma unroll
  for (int hd = 0; hd < HEADS; hd++) {
    float v = as[hd * N_NODES + s] + ad[hd * N_NODES + d];
    v = v >= 0.f ? v : NEG_SLOPE * v;
    v *= w;
    m = fmaxf(m, v);
  }
#pragma unroll
  for (int off = 32; off > 0; off >>= 1) m = fmaxf(m, __shfl_down(m, off));
  __shared__ float red[4];
  int wave = threadIdx.x >> 6, lane = threadIdx.x & 63;
  if (lane == 0) red[wave] = m;
  __syncthreads();
  if (threadIdx.x == 0) {
    float mm = fmaxf(fmaxf(red[0], red[1]), fmaxf(red[2], red[3]));
    atomicMax(gmax, encf(mm));
  }
}

// ---- Kernel 3: single-block chunk-carry exclusive scan of deg[50000] ----
__global__ __launch_bounds__(1024) void k_scan(const int* __restrict__ deg,
                                               int* __restrict__ row_start,
                                               int* __restrict__ cursor) {
  __shared__ int wsum[16];
  int t = threadIdx.x;
  int lane = t & 63, wave = t >> 6;
  int carry = 0;
  for (int base = 0; base < N_NODES; base += 1024) {
    int idx = base + t;
    int val = (idx < N_NODES) ? deg[idx] : 0;
    int v = val;
#pragma unroll
    for (int off = 1; off < 64; off <<= 1) {
      int u = __shfl_up(v, off);
      if (lane >= off) v += u;
    }
    if (lane == 63) wsum[wave] = v;
    __syncthreads();
    int wbase = 0;
#pragma unroll
    for (int w = 0; w < 16; w++) wbase += (w < wave) ? wsum[w] : 0;
    int excl = carry + wbase + v - val;
    if (idx < N_NODES) {
      row_start[idx] = excl;
      cursor[idx] = excl;
    }
    int tot = 0;
#pragma unroll
    for (int w = 0; w < 16; w++) tot += wsum[w];
    carry += tot;
    __syncthreads();
  }
}

// ---- Kernel 4: counting-sort scatter of minimal 8B records (src, ew) ----
__global__ __launch_bounds__(256) void k_scatter(const int* __restrict__ src,
                                                 const int* __restrict__ dst,
                                                 const float* __restrict__ ew,
                                                 int* __restrict__ cursor,
                                                 int2* __restrict__ rec) {
  int e = blockIdx.x * 256 + threadIdx.x;
  int s = src[e], d = dst[e];
  float w = ew[e];
  int pos = atomicAdd(cursor + d, 1);
  rec[pos] = make_int2(s, __float_as_int(w));
}

// ---- Kernel 5: atomic-free aggregation; cooperative per-chunk alphas ----
// One node per block; wave hd = head hd. Chunk of 64 edges: thread (hd,lane)
// computes alpha[hd][lane] once into LDS; inner loop is broadcast reads +
// coalesced h-row gather + FMA.
__global__ __launch_bounds__(256) void k_agg(const int* __restrict__ row_start,
                                             const int* __restrict__ deg,
                                             const int2* __restrict__ rec,
                                             const float* __restrict__ as,
                                             const float* __restrict__ ad,
                                             const unsigned* __restrict__ gmax,
                                             const float* __restrict__ h,
                                             float* __restrict__ out) {
  __shared__ int ss[64];
  __shared__ float sw[64];
  __shared__ float sal[HEADS][64];
  int d = blockIdx.x;
  int t = threadIdx.x;
  int hd = t >> 6, lane = t & 63;
  int rs = row_start[d];
  int dg = deg[d];
  float gm = decf(*gmax);
  float ad_d = ad[hd * N_NODES + d];
  float accv = 0.f;
  float den = 0.f;
  for (int j0 = 0; j0 < dg; j0 += 64) {
    int nj = min(64, dg - j0);
    if (t < nj) {
      int2 r = rec[rs + j0 + t];
      ss[t] = r.x;
      sw[t] = __int_as_float(r.y);
    }
    __syncthreads();
    // cooperative alpha: thread (hd, lane) handles edge `lane`, head `hd`
    float al = 0.f;
    if (lane < nj) {
      int s = ss[lane];
      float v = as[hd * N_NODES + s] + ad_d;
      v = v >= 0.f ? v : NEG_SLOPE * v;
      al = __expf(v * sw[lane] - gm);
    }
    sal[hd][lane] = al;
    __syncthreads();
    int j = 0;
    for (; j + 1 < nj; j += 2) {
      int s0 = ss[j], s1 = ss[j + 1];
      float a0 = sal[hd][j], a1 = sal[hd][j + 1];
      float h0 = h[(size_t)s0 * HF + t];
      float h1 = h[(size_t)s1 * HF + t];
      den += a0 + a1;
      accv += a0 * h0 + a1 * h1;
    }
    if (j < nj) {
      int s0 = ss[j];
      float a0 = sal[hd][j];
      den += a0;
      accv += a0 * h[(size_t)s0 * HF + t];
    }
    __syncthreads();
  }
  out[(size_t)d * HF + t] = accv / (den + 1e-10f);
}

extern "C" void kernel_launch(void* const* d_in, const int* in_sizes, int n_in,
                              void* d_out, int out_size, void* d_ws, size_t ws_size,
                              hipStream_t stream) {
  const float* x     = (const float*)d_in[0];
  const int*   ei    = (const int*)d_in[1];
  const float* ew    = (const float*)d_in[2];
  const float* W     = (const float*)d_in[3];
  const float* a_src = (const float*)d_in[4];
  const float* a_dst = (const float*)d_in[5];
  float* out = (float*)d_out;

  // workspace layout: h | as | ad | deg | row_start | cursor | rec | gmax
  float* h  = (float*)d_ws;                          // 12.8M f
  float* as = h + (size_t)N_NODES * HF;              // 200K f
  float* ad = as + (size_t)HEADS * N_NODES;          // 200K f
  int* deg       = (int*)(ad + (size_t)HEADS * N_NODES);
  int* row_start = deg + N_NODES;
  int* cursor    = row_start + N_NODES;
  int2* rec      = (int2*)(cursor + N_NODES);        // 800K int2
  unsigned* gmax = (unsigned*)(rec + N_EDGES);

  const int* src = ei;
  const int* dst = ei + N_EDGES;

  hipMemsetAsync(deg, 0, (size_t)N_NODES * sizeof(int), stream);
  hipMemsetAsync(gmax, 0, sizeof(unsigned), stream);

  dim3 g1((N_NODES + 63) / 64, HEADS);
  k_gemm<<<g1, 256, 0, stream>>>(x, W, a_src, a_dst, h, as, ad);
  k_edge_max<<<N_EDGES / 256, 256, 0, stream>>>(src, dst, ew, as, ad, gmax, deg);
  k_scan<<<1, 1024, 0, stream>>>(deg, row_start, cursor);
  k_scatter<<<N_EDGES / 256, 256, 0, stream>>>(src, dst, ew, cursor, rec);
  k_agg<<<N_NODES, 256, 0, stream>>>(row_start, deg, rec, as, ad, gmax, h, out);
}

// Round 5
// 424.435 us; speedup vs baseline: 1.1571x; 1.1571x over previous
//
#include <hip/hip_runtime.h>

#define N_NODES 50000
#define N_EDGES 800000
#define IN_F 256
#define OUT_F 64
#define HEADS 4
#define HF 256  // HEADS*OUT_F
#define NEG_SLOPE 0.2f

// ---- monotone float<->uint encoding for atomicMax on floats ----
__device__ __forceinline__ unsigned encf(float f) {
  unsigned u = __float_as_uint(f);
  return (u & 0x80000000u) ? ~u : (u | 0x80000000u);
}
__device__ __forceinline__ float decf(unsigned k) {
  unsigned u = (k & 0x80000000u) ? (k & 0x7FFFFFFFu) : ~k;
  return __uint_as_float(u);
}

// ---- Kernel 1: h = x @ W per head, fused attn-logit epilogue ----
__global__ __launch_bounds__(256) void k_gemm(const float* __restrict__ x,
                                              const float* __restrict__ W,
                                              const float* __restrict__ a_src,
                                              const float* __restrict__ a_dst,
                                              float* __restrict__ h,
                                              float* __restrict__ as_out,
                                              float* __restrict__ ad_out) {
  __shared__ __align__(16) float xs[32][68];
  __shared__ __align__(16) float ws[32][64];
  const int t = threadIdx.x;
  const int n0 = blockIdx.x * 64;
  const int hd = blockIdx.y;
  const int f0 = (t & 15) * 4;
  const int m0 = (t >> 4) * 4;
  const float* Wh = W + hd * (IN_F * OUT_F);

  float acc[4][4];
#pragma unroll
  for (int i = 0; i < 4; i++)
#pragma unroll
    for (int j = 0; j < 4; j++) acc[i][j] = 0.f;

  for (int k0 = 0; k0 < IN_F; k0 += 32) {
#pragma unroll
    for (int qq = 0; qq < 2; qq++) {
      int q = t + qq * 256;
      int row = q >> 3, c4 = q & 7;
      int gr = n0 + row;
      gr = gr < N_NODES ? gr : (N_NODES - 1);
      float4 v = *(const float4*)(x + (size_t)gr * IN_F + k0 + c4 * 4);
      xs[c4 * 4 + 0][row] = v.x;
      xs[c4 * 4 + 1][row] = v.y;
      xs[c4 * 4 + 2][row] = v.z;
      xs[c4 * 4 + 3][row] = v.w;
    }
#pragma unroll
    for (int qq = 0; qq < 2; qq++) {
      int q = t + qq * 256;
      int kk = q >> 4, o4 = q & 15;
      *(float4*)(&ws[kk][o4 * 4]) = *(const float4*)(Wh + (size_t)(k0 + kk) * OUT_F + o4 * 4);
    }
    __syncthreads();
#pragma unroll
    for (int kk = 0; kk < 32; kk++) {
      float4 a = *(const float4*)(&xs[kk][m0]);
      float4 b = *(const float4*)(&ws[kk][f0]);
      acc[0][0] += a.x * b.x; acc[0][1] += a.x * b.y; acc[0][2] += a.x * b.z; acc[0][3] += a.x * b.w;
      acc[1][0] += a.y * b.x; acc[1][1] += a.y * b.y; acc[1][2] += a.y * b.z; acc[1][3] += a.y * b.w;
      acc[2][0] += a.z * b.x; acc[2][1] += a.z * b.y; acc[2][2] += a.z * b.z; acc[2][3] += a.z * b.w;
      acc[3][0] += a.w * b.x; acc[3][1] += a.w * b.y; acc[3][2] += a.w * b.z; acc[3][3] += a.w * b.w;
    }
    __syncthreads();
  }
#pragma unroll
  for (int i = 0; i < 4; i++) {
    int m = n0 + m0 + i;
    if (m < N_NODES) {
      float4 v = make_float4(acc[i][0], acc[i][1], acc[i][2], acc[i][3]);
      *(float4*)(h + (size_t)m * HF + hd * OUT_F + f0) = v;
    }
  }
  // fused attention-logit epilogue
  const float4 asv = *(const float4*)(a_src + hd * OUT_F + f0);
  const float4 adv = *(const float4*)(a_dst + hd * OUT_F + f0);
  float ps[4], pd[4];
#pragma unroll
  for (int i = 0; i < 4; i++) {
    ps[i] = acc[i][0] * asv.x + acc[i][1] * asv.y + acc[i][2] * asv.z + acc[i][3] * asv.w;
    pd[i] = acc[i][0] * adv.x + acc[i][1] * adv.y + acc[i][2] * adv.z + acc[i][3] * adv.w;
  }
#pragma unroll
  for (int off = 8; off > 0; off >>= 1) {
#pragma unroll
    for (int i = 0; i < 4; i++) {
      ps[i] += __shfl_down(ps[i], off, 16);
      pd[i] += __shfl_down(pd[i], off, 16);
    }
  }
  if ((t & 15) == 0) {
#pragma unroll
    for (int i = 0; i < 4; i++) {
      int m = n0 + m0 + i;
      if (m < N_NODES) {
        as_out[hd * N_NODES + m] = ps[i];
        ad_out[hd * N_NODES + m] = pd[i];
      }
    }
  }
}

// ---- Kernel 2: global max of e over [H,E] + dst-degree histogram ----
__global__ __launch_bounds__(256) void k_edge_max(const int* __restrict__ src,
                                                  const int* __restrict__ dst,
                                                  const float* __restrict__ ew,
                                                  const float* __restrict__ as,
                                                  const float* __restrict__ ad,
                                                  unsigned* __restrict__ gmax,
                                                  int* __restrict__ deg) {
  int e = blockIdx.x * 256 + threadIdx.x;
  int s = src[e], d = dst[e];
  float w = ew[e];
  atomicAdd(deg + d, 1);
  float m = -3.4e38f;
#pragma unroll
  for (int hd = 0; hd < HEADS; hd++) {
    float v = as[hd * N_NODES + s] + ad[hd * N_NODES + d];
    v = v >= 0.f ? v : NEG_SLOPE * v;
    v *= w;
    m = fmaxf(m, v);
  }
#pragma unroll
  for (int off = 32; off > 0; off >>= 1) m = fmaxf(m, __shfl_down(m, off));
  __shared__ float red[4];
  int wave = threadIdx.x >> 6, lane = threadIdx.x & 63;
  if (lane == 0) red[wave] = m;
  __syncthreads();
  if (threadIdx.x == 0) {
    float mm = fmaxf(fmaxf(red[0], red[1]), fmaxf(red[2], red[3]));
    atomicMax(gmax, encf(mm));
  }
}

// ---- Scan kernels: exclusive prefix sum of deg[50000] (parallel, 3-stage) ----
__global__ __launch_bounds__(256) void k_scan1(const int* __restrict__ deg,
                                               int* __restrict__ excl,
                                               int* __restrict__ bsum) {
  int i = blockIdx.x * 256 + threadIdx.x;
  int orig = (i < N_NODES) ? deg[i] : 0;
  int v = orig;
  int lane = threadIdx.x & 63, wave = threadIdx.x >> 6;
#pragma unroll
  for (int off = 1; off < 64; off <<= 1) {
    int u = __shfl_up(v, off);
    if (lane >= off) v += u;
  }
  __shared__ int wsum[4];
  if (lane == 63) wsum[wave] = v;
  __syncthreads();
  int base = 0;
  for (int w = 0; w < wave; w++) base += wsum[w];
  int incl = v + base;
  if (i < N_NODES) excl[i] = incl - orig;
  if (threadIdx.x == 255) bsum[blockIdx.x] = incl;
}

__global__ __launch_bounds__(256) void k_scan2(int* __restrict__ bsum, int nb) {
  int t = threadIdx.x;
  int orig = (t < nb) ? bsum[t] : 0;
  int v = orig;
  int lane = t & 63, wave = t >> 6;
#pragma unroll
  for (int off = 1; off < 64; off <<= 1) {
    int u = __shfl_up(v, off);
    if (lane >= off) v += u;
  }
  __shared__ int wsum[4];
  if (lane == 63) wsum[wave] = v;
  __syncthreads();
  int base = 0;
  for (int w = 0; w < wave; w++) base += wsum[w];
  if (t < nb) bsum[t] = v + base - orig;
}

__global__ __launch_bounds__(256) void k_scan3(const int* __restrict__ excl,
                                               const int* __restrict__ bsum,
                                               int* __restrict__ row_start,
                                               int* __restrict__ cursor) {
  int i = blockIdx.x * 256 + threadIdx.x;
  if (i < N_NODES) {
    int rs = excl[i] + bsum[blockIdx.x];
    row_start[i] = rs;
    cursor[i] = rs;
  }
}

// ---- Kernel 4: counting-sort scatter of minimal 8B records (src, ew) ----
__global__ __launch_bounds__(256) void k_scatter(const int* __restrict__ src,
                                                 const int* __restrict__ dst,
                                                 const float* __restrict__ ew,
                                                 int* __restrict__ cursor,
                                                 int2* __restrict__ rec) {
  int e = blockIdx.x * 256 + threadIdx.x;
  int s = src[e], d = dst[e];
  float w = ew[e];
  int pos = atomicAdd(cursor + d, 1);
  rec[pos] = make_int2(s, __float_as_int(w));
}

// ---- Kernel 5: atomic-free aggregation; full-row float4 loads ----
// One node per block. Per 64-edge chunk: alphas computed cooperatively
// (thread (wv,lane) -> edge lane, head wv). Then wave w processes edges
// w, w+4, ... : one 1KB float4 wave-load of h[src], lane l covers feats
// 4l..4l+3 (head = l>>4). Cross-wave LDS reduction at the end.
__global__ __launch_bounds__(256) void k_agg(const int* __restrict__ row_start,
                                             const int* __restrict__ deg,
                                             const int2* __restrict__ rec,
                                             const float* __restrict__ as,
                                             const float* __restrict__ ad,
                                             const unsigned* __restrict__ gmax,
                                             const float* __restrict__ h,
                                             float* __restrict__ out) {
  __shared__ int ss[64];
  __shared__ float sw[64];
  __shared__ float sal[64][4];       // [edge][head]
  __shared__ __align__(16) float4 racc[4][64];
  __shared__ float rden[4][64];
  int d = blockIdx.x;
  int t = threadIdx.x;
  int wv = t >> 6, lane = t & 63;
  int hd4 = lane >> 4;               // head owning feats 4*lane..4*lane+3
  int rs = row_start[d];
  int dg = deg[d];
  float gm = decf(*gmax);
  float ad_w = ad[wv * N_NODES + d]; // for alpha compute (head = wv)
  float4 accv = make_float4(0.f, 0.f, 0.f, 0.f);
  float den = 0.f;
  for (int j0 = 0; j0 < dg; j0 += 64) {
    int nj = min(64, dg - j0);
    if (t < nj) {
      int2 r = rec[rs + j0 + t];
      ss[t] = r.x;
      sw[t] = __int_as_float(r.y);
    }
    __syncthreads();
    // cooperative alpha: thread (wv, lane) -> edge lane, head wv
    float al = 0.f;
    if (lane < nj) {
      int s = ss[lane];
      float v = as[wv * N_NODES + s] + ad_w;
      v = v >= 0.f ? v : NEG_SLOPE * v;
      al = __expf(v * sw[lane] - gm);
    }
    sal[lane][wv] = al;
    __syncthreads();
    // wave wv processes edges wv, wv+4, ... with full-row float4 loads
    int j = wv;
    for (; j + 4 < nj; j += 8) {
      int s0 = ss[j], s1 = ss[j + 4];
      float a0 = sal[j][hd4], a1 = sal[j + 4][hd4];
      float4 h0 = *(const float4*)(h + (size_t)s0 * HF + lane * 4);
      float4 h1 = *(const float4*)(h + (size_t)s1 * HF + lane * 4);
      den += a0 + a1;
      accv.x += a0 * h0.x + a1 * h1.x;
      accv.y += a0 * h0.y + a1 * h1.y;
      accv.z += a0 * h0.z + a1 * h1.z;
      accv.w += a0 * h0.w + a1 * h1.w;
    }
    if (j < nj) {
      int s0 = ss[j];
      float a0 = sal[j][hd4];
      float4 h0 = *(const float4*)(h + (size_t)s0 * HF + lane * 4);
      den += a0;
      accv.x += a0 * h0.x;
      accv.y += a0 * h0.y;
      accv.z += a0 * h0.z;
      accv.w += a0 * h0.w;
    }
    __syncthreads();
  }
  racc[wv][lane] = accv;
  rden[wv][lane] = den;
  __syncthreads();
  if (wv == 0) {
    float4 a0 = racc[0][lane], a1 = racc[1][lane], a2 = racc[2][lane], a3 = racc[3][lane];
    float dn = rden[0][lane] + rden[1][lane] + rden[2][lane] + rden[3][lane] + 1e-10f;
    float inv = 1.f / dn;
    float4 r = make_float4((a0.x + a1.x + a2.x + a3.x) * inv,
                           (a0.y + a1.y + a2.y + a3.y) * inv,
                           (a0.z + a1.z + a2.z + a3.z) * inv,
                           (a0.w + a1.w + a2.w + a3.w) * inv);
    *(float4*)(out + (size_t)d * HF + lane * 4) = r;
  }
}

extern "C" void kernel_launch(void* const* d_in, const int* in_sizes, int n_in,
                              void* d_out, int out_size, void* d_ws, size_t ws_size,
                              hipStream_t stream) {
  const float* x     = (const float*)d_in[0];
  const int*   ei    = (const int*)d_in[1];
  const float* ew    = (const float*)d_in[2];
  const float* W     = (const float*)d_in[3];
  const float* a_src = (const float*)d_in[4];
  const float* a_dst = (const float*)d_in[5];
  float* out = (float*)d_out;

  // workspace layout: h | as | ad | deg | excl | row_start | cursor | rec | bsum | gmax
  float* h  = (float*)d_ws;                          // 12.8M f
  float* as = h + (size_t)N_NODES * HF;              // 200K f
  float* ad = as + (size_t)HEADS * N_NODES;          // 200K f
  int* deg       = (int*)(ad + (size_t)HEADS * N_NODES);
  int* excl      = deg + N_NODES;
  int* row_start = excl + N_NODES;
  int* cursor    = row_start + N_NODES;
  int2* rec      = (int2*)(cursor + N_NODES);        // 800K int2
  int* bsum      = (int*)(rec + N_EDGES);
  unsigned* gmax = (unsigned*)(bsum + 256);

  const int* src = ei;
  const int* dst = ei + N_EDGES;
  const int NB = (N_NODES + 255) / 256;  // 196

  hipMemsetAsync(deg, 0, (size_t)N_NODES * sizeof(int), stream);
  hipMemsetAsync(gmax, 0, sizeof(unsigned), stream);

  dim3 g1((N_NODES + 63) / 64, HEADS);
  k_gemm<<<g1, 256, 0, stream>>>(x, W, a_src, a_dst, h, as, ad);
  k_edge_max<<<N_EDGES / 256, 256, 0, stream>>>(src, dst, ew, as, ad, gmax, deg);
  k_scan1<<<NB, 256, 0, stream>>>(deg, excl, bsum);
  k_scan2<<<1, 256, 0, stream>>>(bsum, NB);
  k_scan3<<<NB, 256, 0, stream>>>(excl, bsum, row_start, cursor);
  k_scatter<<<N_EDGES / 256, 256, 0, stream>>>(src, dst, ew, cursor, rec);
  k_agg<<<N_NODES, 256, 0, stream>>>(row_start, deg, rec, as, ad, gmax, h, out);
}

// Round 6
// 387.864 us; speedup vs baseline: 1.2662x; 1.0943x over previous
//
#include <hip/hip_runtime.h>

#define N_NODES 50000
#define N_EDGES 800000
#define IN_F 256
#define OUT_F 64
#define HEADS 4
#define HF 256  // HEADS*OUT_F
#define NEG_SLOPE 0.2f

// ---- monotone float<->uint encoding for atomicMax on floats ----
__device__ __forceinline__ unsigned encf(float f) {
  unsigned u = __float_as_uint(f);
  return (u & 0x80000000u) ? ~u : (u | 0x80000000u);
}
__device__ __forceinline__ float decf(unsigned k) {
  unsigned u = (k & 0x80000000u) ? (k & 0x7FFFFFFFu) : ~k;
  return __uint_as_float(u);
}
// fp32 -> bf16 (round-to-nearest-even), manual to avoid type plumbing
__device__ __forceinline__ unsigned short f2bf(float f) {
  unsigned u = __float_as_uint(f);
  u += 0x7FFFu + ((u >> 16) & 1u);
  return (unsigned short)(u >> 16);
}

// ---- Kernel 1: h = x @ W per head (h stored bf16), fused attn-logit epilogue
__global__ __launch_bounds__(256) void k_gemm(const float* __restrict__ x,
                                              const float* __restrict__ W,
                                              const float* __restrict__ a_src,
                                              const float* __restrict__ a_dst,
                                              unsigned short* __restrict__ hb,
                                              float* __restrict__ as_out,
                                              float* __restrict__ ad_out) {
  __shared__ __align__(16) float xs[32][68];
  __shared__ __align__(16) float ws[32][64];
  const int t = threadIdx.x;
  const int n0 = blockIdx.x * 64;
  const int hd = blockIdx.y;
  const int f0 = (t & 15) * 4;
  const int m0 = (t >> 4) * 4;
  const float* Wh = W + hd * (IN_F * OUT_F);

  float acc[4][4];
#pragma unroll
  for (int i = 0; i < 4; i++)
#pragma unroll
    for (int j = 0; j < 4; j++) acc[i][j] = 0.f;

  for (int k0 = 0; k0 < IN_F; k0 += 32) {
#pragma unroll
    for (int qq = 0; qq < 2; qq++) {
      int q = t + qq * 256;
      int row = q >> 3, c4 = q & 7;
      int gr = n0 + row;
      gr = gr < N_NODES ? gr : (N_NODES - 1);
      float4 v = *(const float4*)(x + (size_t)gr * IN_F + k0 + c4 * 4);
      xs[c4 * 4 + 0][row] = v.x;
      xs[c4 * 4 + 1][row] = v.y;
      xs[c4 * 4 + 2][row] = v.z;
      xs[c4 * 4 + 3][row] = v.w;
    }
#pragma unroll
    for (int qq = 0; qq < 2; qq++) {
      int q = t + qq * 256;
      int kk = q >> 4, o4 = q & 15;
      *(float4*)(&ws[kk][o4 * 4]) = *(const float4*)(Wh + (size_t)(k0 + kk) * OUT_F + o4 * 4);
    }
    __syncthreads();
#pragma unroll
    for (int kk = 0; kk < 32; kk++) {
      float4 a = *(const float4*)(&xs[kk][m0]);
      float4 b = *(const float4*)(&ws[kk][f0]);
      acc[0][0] += a.x * b.x; acc[0][1] += a.x * b.y; acc[0][2] += a.x * b.z; acc[0][3] += a.x * b.w;
      acc[1][0] += a.y * b.x; acc[1][1] += a.y * b.y; acc[1][2] += a.y * b.z; acc[1][3] += a.y * b.w;
      acc[2][0] += a.z * b.x; acc[2][1] += a.z * b.y; acc[2][2] += a.z * b.z; acc[2][3] += a.z * b.w;
      acc[3][0] += a.w * b.x; acc[3][1] += a.w * b.y; acc[3][2] += a.w * b.z; acc[3][3] += a.w * b.w;
    }
    __syncthreads();
  }
#pragma unroll
  for (int i = 0; i < 4; i++) {
    int m = n0 + m0 + i;
    if (m < N_NODES) {
      ushort4 v = make_ushort4(f2bf(acc[i][0]), f2bf(acc[i][1]),
                               f2bf(acc[i][2]), f2bf(acc[i][3]));
      *(ushort4*)(hb + (size_t)m * HF + hd * OUT_F + f0) = v;
    }
  }
  // fused attention-logit epilogue (from fp32 accumulators)
  const float4 asv = *(const float4*)(a_src + hd * OUT_F + f0);
  const float4 adv = *(const float4*)(a_dst + hd * OUT_F + f0);
  float ps[4], pd[4];
#pragma unroll
  for (int i = 0; i < 4; i++) {
    ps[i] = acc[i][0] * asv.x + acc[i][1] * asv.y + acc[i][2] * asv.z + acc[i][3] * asv.w;
    pd[i] = acc[i][0] * adv.x + acc[i][1] * adv.y + acc[i][2] * adv.z + acc[i][3] * adv.w;
  }
#pragma unroll
  for (int off = 8; off > 0; off >>= 1) {
#pragma unroll
    for (int i = 0; i < 4; i++) {
      ps[i] += __shfl_down(ps[i], off, 16);
      pd[i] += __shfl_down(pd[i], off, 16);
    }
  }
  if ((t & 15) == 0) {
#pragma unroll
    for (int i = 0; i < 4; i++) {
      int m = n0 + m0 + i;
      if (m < N_NODES) {
        as_out[hd * N_NODES + m] = ps[i];
        ad_out[hd * N_NODES + m] = pd[i];
      }
    }
  }
}

// ---- Kernel 2: global max of e over [H,E] + dst-degree histogram ----
__global__ __launch_bounds__(256) void k_edge_max(const int* __restrict__ src,
                                                  const int* __restrict__ dst,
                                                  const float* __restrict__ ew,
                                                  const float* __restrict__ as,
                                                  const float* __restrict__ ad,
                                                  unsigned* __restrict__ gmax,
                                                  int* __restrict__ deg) {
  int e = blockIdx.x * 256 + threadIdx.x;
  int s = src[e], d = dst[e];
  float w = ew[e];
  atomicAdd(deg + d, 1);
  float m = -3.4e38f;
#pragma unroll
  for (int hd = 0; hd < HEADS; hd++) {
    float v = as[hd * N_NODES + s] + ad[hd * N_NODES + d];
    v = v >= 0.f ? v : NEG_SLOPE * v;
    v *= w;
    m = fmaxf(m, v);
  }
#pragma unroll
  for (int off = 32; off > 0; off >>= 1) m = fmaxf(m, __shfl_down(m, off));
  __shared__ float red[4];
  int wave = threadIdx.x >> 6, lane = threadIdx.x & 63;
  if (lane == 0) red[wave] = m;
  __syncthreads();
  if (threadIdx.x == 0) {
    float mm = fmaxf(fmaxf(red[0], red[1]), fmaxf(red[2], red[3]));
    atomicMax(gmax, encf(mm));
  }
}

// ---- Scan kernels: exclusive prefix sum of deg[50000] (parallel, 3-stage) ----
__global__ __launch_bounds__(256) void k_scan1(const int* __restrict__ deg,
                                               int* __restrict__ excl,
                                               int* __restrict__ bsum) {
  int i = blockIdx.x * 256 + threadIdx.x;
  int orig = (i < N_NODES) ? deg[i] : 0;
  int v = orig;
  int lane = threadIdx.x & 63, wave = threadIdx.x >> 6;
#pragma unroll
  for (int off = 1; off < 64; off <<= 1) {
    int u = __shfl_up(v, off);
    if (lane >= off) v += u;
  }
  __shared__ int wsum[4];
  if (lane == 63) wsum[wave] = v;
  __syncthreads();
  int base = 0;
  for (int w = 0; w < wave; w++) base += wsum[w];
  int incl = v + base;
  if (i < N_NODES) excl[i] = incl - orig;
  if (threadIdx.x == 255) bsum[blockIdx.x] = incl;
}

__global__ __launch_bounds__(256) void k_scan2(int* __restrict__ bsum, int nb) {
  int t = threadIdx.x;
  int orig = (t < nb) ? bsum[t] : 0;
  int v = orig;
  int lane = t & 63, wave = t >> 6;
#pragma unroll
  for (int off = 1; off < 64; off <<= 1) {
    int u = __shfl_up(v, off);
    if (lane >= off) v += u;
  }
  __shared__ int wsum[4];
  if (lane == 63) wsum[wave] = v;
  __syncthreads();
  int base = 0;
  for (int w = 0; w < wave; w++) base += wsum[w];
  if (t < nb) bsum[t] = v + base - orig;
}

__global__ __launch_bounds__(256) void k_scan3(const int* __restrict__ excl,
                                               const int* __restrict__ bsum,
                                               int* __restrict__ row_start,
                                               int* __restrict__ cursor) {
  int i = blockIdx.x * 256 + threadIdx.x;
  if (i < N_NODES) {
    int rs = excl[i] + bsum[blockIdx.x];
    row_start[i] = rs;
    cursor[i] = rs;
  }
}

// ---- Kernel 4: counting-sort scatter of minimal 8B records (src, ew) ----
__global__ __launch_bounds__(256) void k_scatter(const int* __restrict__ src,
                                                 const int* __restrict__ dst,
                                                 const float* __restrict__ ew,
                                                 int* __restrict__ cursor,
                                                 int2* __restrict__ rec) {
  int e = blockIdx.x * 256 + threadIdx.x;
  int s = src[e], d = dst[e];
  float w = ew[e];
  int pos = atomicAdd(cursor + d, 1);
  rec[pos] = make_int2(s, __float_as_int(w));
}

// ---- Kernel 5: atomic-free aggregation; bf16 h rows (512B wave-loads) ----
// One node per block. Per 64-edge chunk: alphas cooperative (thread (wv,lane)
// -> edge lane, head wv). Wave w processes edges w, w+4, ...: one 512B
// uint2 wave-load of hb[src], lane l covers feats 4l..4l+3. Cross-wave LDS
// reduction at the end.
__global__ __launch_bounds__(256) void k_agg(const int* __restrict__ row_start,
                                             const int* __restrict__ deg,
                                             const int2* __restrict__ rec,
                                             const float* __restrict__ as,
                                             const float* __restrict__ ad,
                                             const unsigned* __restrict__ gmax,
                                             const unsigned short* __restrict__ hb,
                                             float* __restrict__ out) {
  __shared__ int ss[64];
  __shared__ float sw[64];
  __shared__ float sal[4][65];       // [head][edge], padded: stride 65 banks
  __shared__ __align__(16) float4 racc[4][64];
  __shared__ float rden[4][64];
  int d = blockIdx.x;
  int t = threadIdx.x;
  int wv = t >> 6, lane = t & 63;
  int hd4 = lane >> 4;               // head owning feats 4*lane..4*lane+3
  int rs = row_start[d];
  int dg = deg[d];
  float gm = decf(*gmax);
  float ad_w = ad[wv * N_NODES + d];
  float4 accv = make_float4(0.f, 0.f, 0.f, 0.f);
  float den = 0.f;
  for (int j0 = 0; j0 < dg; j0 += 64) {
    int nj = min(64, dg - j0);
    if (t < nj) {
      int2 r = rec[rs + j0 + t];
      ss[t] = r.x;
      sw[t] = __int_as_float(r.y);
    }
    __syncthreads();
    float al = 0.f;
    if (lane < nj) {
      int s = ss[lane];
      float v = as[wv * N_NODES + s] + ad_w;
      v = v >= 0.f ? v : NEG_SLOPE * v;
      al = __expf(v * sw[lane] - gm);
    }
    sal[wv][lane] = al;
    __syncthreads();
    int j = wv;
    for (; j + 4 < nj; j += 8) {
      int s0 = ss[j], s1 = ss[j + 4];
      float a0 = sal[hd4][j], a1 = sal[hd4][j + 4];
      uint2 q0 = *(const uint2*)(hb + (size_t)s0 * HF + lane * 4);
      uint2 q1 = *(const uint2*)(hb + (size_t)s1 * HF + lane * 4);
      den += a0 + a1;
      accv.x += a0 * __uint_as_float(q0.x << 16)          + a1 * __uint_as_float(q1.x << 16);
      accv.y += a0 * __uint_as_float(q0.x & 0xFFFF0000u)  + a1 * __uint_as_float(q1.x & 0xFFFF0000u);
      accv.z += a0 * __uint_as_float(q0.y << 16)          + a1 * __uint_as_float(q1.y << 16);
      accv.w += a0 * __uint_as_float(q0.y & 0xFFFF0000u)  + a1 * __uint_as_float(q1.y & 0xFFFF0000u);
    }
    if (j < nj) {
      int s0 = ss[j];
      float a0 = sal[hd4][j];
      uint2 q0 = *(const uint2*)(hb + (size_t)s0 * HF + lane * 4);
      den += a0;
      accv.x += a0 * __uint_as_float(q0.x << 16);
      accv.y += a0 * __uint_as_float(q0.x & 0xFFFF0000u);
      accv.z += a0 * __uint_as_float(q0.y << 16);
      accv.w += a0 * __uint_as_float(q0.y & 0xFFFF0000u);
    }
    __syncthreads();
  }
  racc[wv][lane] = accv;
  rden[wv][lane] = den;
  __syncthreads();
  if (wv == 0) {
    float4 a0 = racc[0][lane], a1 = racc[1][lane], a2 = racc[2][lane], a3 = racc[3][lane];
    float dn = rden[0][lane] + rden[1][lane] + rden[2][lane] + rden[3][lane] + 1e-10f;
    float inv = 1.f / dn;
    float4 r = make_float4((a0.x + a1.x + a2.x + a3.x) * inv,
                           (a0.y + a1.y + a2.y + a3.y) * inv,
                           (a0.z + a1.z + a2.z + a3.z) * inv,
                           (a0.w + a1.w + a2.w + a3.w) * inv);
    *(float4*)(out + (size_t)d * HF + lane * 4) = r;
  }
}

extern "C" void kernel_launch(void* const* d_in, const int* in_sizes, int n_in,
                              void* d_out, int out_size, void* d_ws, size_t ws_size,
                              hipStream_t stream) {
  const float* x     = (const float*)d_in[0];
  const int*   ei    = (const int*)d_in[1];
  const float* ew    = (const float*)d_in[2];
  const float* W     = (const float*)d_in[3];
  const float* a_src = (const float*)d_in[4];
  const float* a_dst = (const float*)d_in[5];
  float* out = (float*)d_out;

  // workspace layout: hb(bf16) | as | ad | deg | excl | row_start | cursor |
  //   rec | bsum | gmax
  unsigned short* hb = (unsigned short*)d_ws;            // 12.8M ushort
  float* as = (float*)(hb + (size_t)N_NODES * HF);       // 200K f
  float* ad = as + (size_t)HEADS * N_NODES;              // 200K f
  int* deg       = (int*)(ad + (size_t)HEADS * N_NODES);
  int* excl      = deg + N_NODES;
  int* row_start = excl + N_NODES;
  int* cursor    = row_start + N_NODES;
  int2* rec      = (int2*)(cursor + N_NODES);            // 800K int2
  int* bsum      = (int*)(rec + N_EDGES);
  unsigned* gmax = (unsigned*)(bsum + 256);

  const int* src = ei;
  const int* dst = ei + N_EDGES;
  const int NB = (N_NODES + 255) / 256;  // 196

  hipMemsetAsync(deg, 0, (size_t)N_NODES * sizeof(int), stream);
  hipMemsetAsync(gmax, 0, sizeof(unsigned), stream);

  dim3 g1((N_NODES + 63) / 64, HEADS);
  k_gemm<<<g1, 256, 0, stream>>>(x, W, a_src, a_dst, hb, as, ad);
  k_edge_max<<<N_EDGES / 256, 256, 0, stream>>>(src, dst, ew, as, ad, gmax, deg);
  k_scan1<<<NB, 256, 0, stream>>>(deg, excl, bsum);
  k_scan2<<<1, 256, 0, stream>>>(bsum, NB);
  k_scan3<<<NB, 256, 0, stream>>>(excl, bsum, row_start, cursor);
  k_scatter<<<N_EDGES / 256, 256, 0, stream>>>(src, dst, ew, cursor, rec);
  k_agg<<<N_NODES, 256, 0, stream>>>(row_start, deg, rec, as, ad, gmax, hb, out);
}

// Round 7
// 329.924 us; speedup vs baseline: 1.4885x; 1.1756x over previous
//
#include <hip/hip_runtime.h>

#define N_NODES 50000
#define N_EDGES 800000
#define IN_F 256
#define OUT_F 64
#define HEADS 4
#define HF 256  // HEADS*OUT_F
#define NEG_SLOPE 0.2f

typedef __bf16 bf16x8 __attribute__((ext_vector_type(8)));
typedef float f32x4 __attribute__((ext_vector_type(4)));

// ---- monotone float<->uint encoding for atomicMax on floats ----
__device__ __forceinline__ unsigned encf(float f) {
  unsigned u = __float_as_uint(f);
  return (u & 0x80000000u) ? ~u : (u | 0x80000000u);
}
__device__ __forceinline__ float decf(unsigned k) {
  unsigned u = (k & 0x80000000u) ? (k & 0x7FFFFFFFu) : ~k;
  return __uint_as_float(u);
}
// fp32 -> bf16 (round-to-nearest-even)
__device__ __forceinline__ unsigned short f2bf(float f) {
  unsigned u = __float_as_uint(f);
  u += 0x7FFFu + ((u >> 16) & 1u);
  return (unsigned short)(u >> 16);
}

// ---- Pack x into MFMA A-fragment layout (bf16) ----
// xp[((mt*8 + kt)*64 + l)*8 + j] = bf16(x[mt*16 + (l&15)][kt*32 + (l>>4)*8 + j])
// N_NODES = 3125 * 16 exactly.
__global__ __launch_bounds__(256) void k_pack_x(const float* __restrict__ x,
                                                unsigned short* __restrict__ xp) {
  int tid = blockIdx.x * 256 + threadIdx.x;  // 3125*8*64 = 1.6M
  int l = tid & 63;
  int kt = (tid >> 6) & 7;
  int mt = tid >> 9;
  int m = mt * 16 + (l & 15);
  int kb = kt * 32 + (l >> 4) * 8;
  const float* px = x + (size_t)m * IN_F + kb;
  float4 v0 = *(const float4*)px;
  float4 v1 = *(const float4*)(px + 4);
  uint4 o;
  o.x = (unsigned)f2bf(v0.x) | ((unsigned)f2bf(v0.y) << 16);
  o.y = (unsigned)f2bf(v0.z) | ((unsigned)f2bf(v0.w) << 16);
  o.z = (unsigned)f2bf(v1.x) | ((unsigned)f2bf(v1.y) << 16);
  o.w = (unsigned)f2bf(v1.z) | ((unsigned)f2bf(v1.w) << 16);
  *(uint4*)(xp + (size_t)tid * 8) = o;
}

// ---- Pack W into MFMA B-fragment layout (bf16) ----
// wb[((hd*4+w)*8 + kt)*512 + l*8 + j] = bf16(W[hd][kt*32+(l>>4)*8+j][w*16+(l&15)])
__global__ __launch_bounds__(256) void k_pack_w(const float* __restrict__ W,
                                                unsigned short* __restrict__ wb) {
  int idx = blockIdx.x * 256 + threadIdx.x;  // 65536
  int j = idx & 7, l = (idx >> 3) & 63, kt = (idx >> 9) & 7;
  int w = (idx >> 12) & 3, hd = (idx >> 14) & 3;
  int k = kt * 32 + (l >> 4) * 8 + j;
  int o = w * 16 + (l & 15);
  wb[idx] = f2bf(W[((size_t)hd * IN_F + k) * OUT_F + o]);
}

// ---- Kernel 1: MFMA GEMM h = x@W (bf16 in, fp32 acc, bf16 h out) ----
// Block = 64 rows x one head (64 cols). Wave w owns cols w*16..w*16+15.
// 4 C-frags per wave (M-subtiles), K-loop 8 x 32. No operand LDS.
// Fused attn-logit epilogue from fp32 accumulators.
__global__ __launch_bounds__(256) void k_gemm(const unsigned short* __restrict__ xp,
                                              const unsigned short* __restrict__ wb,
                                              const float* __restrict__ a_src,
                                              const float* __restrict__ a_dst,
                                              unsigned short* __restrict__ hb,
                                              float* __restrict__ as_out,
                                              float* __restrict__ ad_out) {
  __shared__ float att[2][4][64];
  const int t = threadIdx.x;
  const int w = t >> 6, l = t & 63;
  const int quad = l >> 4, col = l & 15;
  const int hd = blockIdx.y;
  const int blk = blockIdx.x;
  f32x4 acc[4];
#pragma unroll
  for (int ms = 0; ms < 4; ms++) acc[ms] = (f32x4){0.f, 0.f, 0.f, 0.f};

  const unsigned short* wbase = wb + (size_t)(hd * 4 + w) * 4096 + l * 8;
  size_t ab[4];
#pragma unroll
  for (int ms = 0; ms < 4; ms++) {
    int mt = blk * 4 + ms;
    if (mt > 3124) mt = 3124;  // tail block: rows discarded on store
    ab[ms] = (size_t)mt * 4096 + l * 8;
  }
  for (int kt = 0; kt < 8; kt++) {
    union { uint4 u; bf16x8 v; } b, a0, a1, a2, a3;
    b.u  = *(const uint4*)(wbase + kt * 512);
    a0.u = *(const uint4*)(xp + ab[0] + kt * 512);
    a1.u = *(const uint4*)(xp + ab[1] + kt * 512);
    a2.u = *(const uint4*)(xp + ab[2] + kt * 512);
    a3.u = *(const uint4*)(xp + ab[3] + kt * 512);
    acc[0] = __builtin_amdgcn_mfma_f32_16x16x32_bf16(a0.v, b.v, acc[0], 0, 0, 0);
    acc[1] = __builtin_amdgcn_mfma_f32_16x16x32_bf16(a1.v, b.v, acc[1], 0, 0, 0);
    acc[2] = __builtin_amdgcn_mfma_f32_16x16x32_bf16(a2.v, b.v, acc[2], 0, 0, 0);
    acc[3] = __builtin_amdgcn_mfma_f32_16x16x32_bf16(a3.v, b.v, acc[3], 0, 0, 0);
  }
  // C/D layout: col = lane&15, row = quad*4 + reg  [verified m89/m91]
  const float avs = a_src[hd * OUT_F + w * 16 + col];
  const float avd = a_dst[hd * OUT_F + w * 16 + col];
#pragma unroll
  for (int ms = 0; ms < 4; ms++) {
#pragma unroll
    for (int r = 0; r < 4; r++) {
      float hv = acc[ms][r];
      int m = blk * 64 + ms * 16 + quad * 4 + r;
      if (m < N_NODES)
        hb[(size_t)m * HF + hd * OUT_F + w * 16 + col] = f2bf(hv);
      float ps = hv * avs, pd = hv * avd;
#pragma unroll
      for (int off = 8; off > 0; off >>= 1) {
        ps += __shfl_down(ps, off, 16);
        pd += __shfl_down(pd, off, 16);
      }
      if (col == 0) {
        att[0][w][ms * 16 + quad * 4 + r] = ps;
        att[1][w][ms * 16 + quad * 4 + r] = pd;
      }
    }
  }
  __syncthreads();
  if (t < 64) {
    int m = blk * 64 + t;
    if (m < N_NODES) {
      as_out[hd * N_NODES + m] = att[0][0][t] + att[0][1][t] + att[0][2][t] + att[0][3][t];
      ad_out[hd * N_NODES + m] = att[1][0][t] + att[1][1][t] + att[1][2][t] + att[1][3][t];
    }
  }
}

// ---- Kernel 2: global max of e over [H,E] + dst-degree histogram ----
__global__ __launch_bounds__(256) void k_edge_max(const int* __restrict__ src,
                                                  const int* __restrict__ dst,
                                                  const float* __restrict__ ew,
                                                  const float* __restrict__ as,
                                                  const float* __restrict__ ad,
                                                  unsigned* __restrict__ gmax,
                                                  int* __restrict__ deg) {
  int e = blockIdx.x * 256 + threadIdx.x;
  int s = src[e], d = dst[e];
  float w = ew[e];
  atomicAdd(deg + d, 1);
  float m = -3.4e38f;
#pragma unroll
  for (int hd = 0; hd < HEADS; hd++) {
    float v = as[hd * N_NODES + s] + ad[hd * N_NODES + d];
    v = v >= 0.f ? v : NEG_SLOPE * v;
    v *= w;
    m = fmaxf(m, v);
  }
#pragma unroll
  for (int off = 32; off > 0; off >>= 1) m = fmaxf(m, __shfl_down(m, off));
  __shared__ float red[4];
  int wave = threadIdx.x >> 6, lane = threadIdx.x & 63;
  if (lane == 0) red[wave] = m;
  __syncthreads();
  if (threadIdx.x == 0) {
    float mm = fmaxf(fmaxf(red[0], red[1]), fmaxf(red[2], red[3]));
    atomicMax(gmax, encf(mm));
  }
}

// ---- Scan kernels: exclusive prefix sum of deg[50000] (parallel, 3-stage) ----
__global__ __launch_bounds__(256) void k_scan1(const int* __restrict__ deg,
                                               int* __restrict__ excl,
                                               int* __restrict__ bsum) {
  int i = blockIdx.x * 256 + threadIdx.x;
  int orig = (i < N_NODES) ? deg[i] : 0;
  int v = orig;
  int lane = threadIdx.x & 63, wave = threadIdx.x >> 6;
#pragma unroll
  for (int off = 1; off < 64; off <<= 1) {
    int u = __shfl_up(v, off);
    if (lane >= off) v += u;
  }
  __shared__ int wsum[4];
  if (lane == 63) wsum[wave] = v;
  __syncthreads();
  int base = 0;
  for (int w = 0; w < wave; w++) base += wsum[w];
  int incl = v + base;
  if (i < N_NODES) excl[i] = incl - orig;
  if (threadIdx.x == 255) bsum[blockIdx.x] = incl;
}

__global__ __launch_bounds__(256) void k_scan2(int* __restrict__ bsum, int nb) {
  int t = threadIdx.x;
  int orig = (t < nb) ? bsum[t] : 0;
  int v = orig;
  int lane = t & 63, wave = t >> 6;
#pragma unroll
  for (int off = 1; off < 64; off <<= 1) {
    int u = __shfl_up(v, off);
    if (lane >= off) v += u;
  }
  __shared__ int wsum[4];
  if (lane == 63) wsum[wave] = v;
  __syncthreads();
  int base = 0;
  for (int w = 0; w < wave; w++) base += wsum[w];
  if (t < nb) bsum[t] = v + base - orig;
}

__global__ __launch_bounds__(256) void k_scan3(const int* __restrict__ excl,
                                               const int* __restrict__ bsum,
                                               int* __restrict__ row_start,
                                               int* __restrict__ cursor) {
  int i = blockIdx.x * 256 + threadIdx.x;
  if (i < N_NODES) {
    int rs = excl[i] + bsum[blockIdx.x];
    row_start[i] = rs;
    cursor[i] = rs;
  }
}

// ---- Kernel 4: counting-sort scatter of minimal 8B records (src, ew) ----
__global__ __launch_bounds__(256) void k_scatter(const int* __restrict__ src,
                                                 const int* __restrict__ dst,
                                                 const float* __restrict__ ew,
                                                 int* __restrict__ cursor,
                                                 int2* __restrict__ rec) {
  int e = blockIdx.x * 256 + threadIdx.x;
  int s = src[e], d = dst[e];
  float w = ew[e];
  int pos = atomicAdd(cursor + d, 1);
  rec[pos] = make_int2(s, __float_as_int(w));
}

// ---- Kernel 5: atomic-free aggregation; bf16 h rows (512B wave-loads) ----
__global__ __launch_bounds__(256) void k_agg(const int* __restrict__ row_start,
                                             const int* __restrict__ deg,
                                             const int2* __restrict__ rec,
                                             const float* __restrict__ as,
                                             const float* __restrict__ ad,
                                             const unsigned* __restrict__ gmax,
                                             const unsigned short* __restrict__ hb,
                                             float* __restrict__ out) {
  __shared__ int ss[64];
  __shared__ float sw[64];
  __shared__ float sal[4][65];       // [head][edge], padded
  __shared__ __align__(16) float4 racc[4][64];
  __shared__ float rden[4][64];
  int d = blockIdx.x;
  int t = threadIdx.x;
  int wv = t >> 6, lane = t & 63;
  int hd4 = lane >> 4;
  int rs = row_start[d];
  int dg = deg[d];
  float gm = decf(*gmax);
  float ad_w = ad[wv * N_NODES + d];
  float4 accv = make_float4(0.f, 0.f, 0.f, 0.f);
  float den = 0.f;
  for (int j0 = 0; j0 < dg; j0 += 64) {
    int nj = min(64, dg - j0);
    if (t < nj) {
      int2 r = rec[rs + j0 + t];
      ss[t] = r.x;
      sw[t] = __int_as_float(r.y);
    }
    __syncthreads();
    float al = 0.f;
    if (lane < nj) {
      int s = ss[lane];
      float v = as[wv * N_NODES + s] + ad_w;
      v = v >= 0.f ? v : NEG_SLOPE * v;
      al = __expf(v * sw[lane] - gm);
    }
    sal[wv][lane] = al;
    __syncthreads();
    int j = wv;
    for (; j + 4 < nj; j += 8) {
      int s0 = ss[j], s1 = ss[j + 4];
      float a0 = sal[hd4][j], a1 = sal[hd4][j + 4];
      uint2 q0 = *(const uint2*)(hb + (size_t)s0 * HF + lane * 4);
      uint2 q1 = *(const uint2*)(hb + (size_t)s1 * HF + lane * 4);
      den += a0 + a1;
      accv.x += a0 * __uint_as_float(q0.x << 16)         + a1 * __uint_as_float(q1.x << 16);
      accv.y += a0 * __uint_as_float(q0.x & 0xFFFF0000u) + a1 * __uint_as_float(q1.x & 0xFFFF0000u);
      accv.z += a0 * __uint_as_float(q0.y << 16)         + a1 * __uint_as_float(q1.y << 16);
      accv.w += a0 * __uint_as_float(q0.y & 0xFFFF0000u) + a1 * __uint_as_float(q1.y & 0xFFFF0000u);
    }
    if (j < nj) {
      int s0 = ss[j];
      float a0 = sal[hd4][j];
      uint2 q0 = *(const uint2*)(hb + (size_t)s0 * HF + lane * 4);
      den += a0;
      accv.x += a0 * __uint_as_float(q0.x << 16);
      accv.y += a0 * __uint_as_float(q0.x & 0xFFFF0000u);
      accv.z += a0 * __uint_as_float(q0.y << 16);
      accv.w += a0 * __uint_as_float(q0.y & 0xFFFF0000u);
    }
    __syncthreads();
  }
  racc[wv][lane] = accv;
  rden[wv][lane] = den;
  __syncthreads();
  if (wv == 0) {
    float4 a0 = racc[0][lane], a1 = racc[1][lane], a2 = racc[2][lane], a3 = racc[3][lane];
    float dn = rden[0][lane] + rden[1][lane] + rden[2][lane] + rden[3][lane] + 1e-10f;
    float inv = 1.f / dn;
    float4 r = make_float4((a0.x + a1.x + a2.x + a3.x) * inv,
                           (a0.y + a1.y + a2.y + a3.y) * inv,
                           (a0.z + a1.z + a2.z + a3.z) * inv,
                           (a0.w + a1.w + a2.w + a3.w) * inv);
    *(float4*)(out + (size_t)d * HF + lane * 4) = r;
  }
}

extern "C" void kernel_launch(void* const* d_in, const int* in_sizes, int n_in,
                              void* d_out, int out_size, void* d_ws, size_t ws_size,
                              hipStream_t stream) {
  const float* x     = (const float*)d_in[0];
  const int*   ei    = (const int*)d_in[1];
  const float* ew    = (const float*)d_in[2];
  const float* W     = (const float*)d_in[3];
  const float* a_src = (const float*)d_in[4];
  const float* a_dst = (const float*)d_in[5];
  float* out = (float*)d_out;

  // workspace: hb | xp | wb | as | ad | deg | excl | row_start | cursor | rec | bsum | gmax
  unsigned short* hb = (unsigned short*)d_ws;            // 12.8M ushort (25.6 MB)
  unsigned short* xp = hb + (size_t)N_NODES * HF;        // 12.8M ushort (25.6 MB)
  unsigned short* wbp = xp + (size_t)N_NODES * IN_F;     // 65536 ushort
  float* as = (float*)(wbp + 65536);                     // 200K f
  float* ad = as + (size_t)HEADS * N_NODES;              // 200K f
  int* deg       = (int*)(ad + (size_t)HEADS * N_NODES);
  int* excl      = deg + N_NODES;
  int* row_start = excl + N_NODES;
  int* cursor    = row_start + N_NODES;
  int2* rec      = (int2*)(cursor + N_NODES);            // 800K int2
  int* bsum      = (int*)(rec + N_EDGES);
  unsigned* gmax = (unsigned*)(bsum + 256);

  const int* src = ei;
  const int* dst = ei + N_EDGES;
  const int NB = (N_NODES + 255) / 256;  // 196

  hipMemsetAsync(deg, 0, (size_t)N_NODES * sizeof(int), stream);
  hipMemsetAsync(gmax, 0, sizeof(unsigned), stream);

  k_pack_w<<<256, 256, 0, stream>>>(W, wbp);
  k_pack_x<<<6250, 256, 0, stream>>>(x, xp);
  dim3 g1(782, HEADS);
  k_gemm<<<g1, 256, 0, stream>>>(xp, wbp, a_src, a_dst, hb, as, ad);
  k_edge_max<<<N_EDGES / 256, 256, 0, stream>>>(src, dst, ew, as, ad, gmax, deg);
  k_scan1<<<NB, 256, 0, stream>>>(deg, excl, bsum);
  k_scan2<<<1, 256, 0, stream>>>(bsum, NB);
  k_scan3<<<NB, 256, 0, stream>>>(excl, bsum, row_start, cursor);
  k_scatter<<<N_EDGES / 256, 256, 0, stream>>>(src, dst, ew, cursor, rec);
  k_agg<<<N_NODES, 256, 0, stream>>>(row_start, deg, rec, as, ad, gmax, hb, out);
}